// Round 9
// baseline (76.368 us; speedup 1.0000x reference)
//
#include <hip/hip_runtime.h>
#include <hip/hip_bf16.h>
#include <stdint.h>

// Problem: B=1024, IN=20000, NG=64, GIN=512, H1=256, GS=128
// o = x[:,idx] @ (W1@W2) + (b1@W2 + b2)   -- linear-linear collapse
//
// ws layout: G bf16 [64][1024][512] @0 (64MiB), Wc bf16 [64][128][512] @64MiB (8MiB),
//            bias2 f32 [64][128] @72MiB (32KB). Requires ws_size >= 72MiB+32KB.
//
// R9: fat prep, dynamic LDS 80KB -> 2 blocks/CU. Gather role: 2 rows/block,
// TWO bf16 row buffers (40KB each), per-row pipeline (issue row1 f32 loads
// before gather(row0); cvt+write row1 needs no barrier: disjoint buffer).
// idx hoisted PACKED 2x16b/VGPR (16 regs) so gather phase has zero vmem loads
// (no forced vmcnt drain) and block stays under 64 VGPR for 8 waves/SIMD.

typedef __attribute__((ext_vector_type(4))) float f32x4;
typedef __attribute__((ext_vector_type(8))) __bf16 bf16x8;
typedef __attribute__((ext_vector_type(8))) uint16_t u16x8;

__device__ __forceinline__ uint16_t f2bf(float f) {
    uint32_t u = __float_as_uint(f);
    u += 0x7FFFu + ((u >> 16) & 1u);   // RNE
    return (uint16_t)(u >> 16);
}

__device__ __forceinline__ uint64_t pack4bf(f32x4 v) {
    return (uint64_t)f2bf(v[0]) | ((uint64_t)f2bf(v[1]) << 16)
         | ((uint64_t)f2bf(v[2]) << 32) | ((uint64_t)f2bf(v[3]) << 48);
}

// stage one f32x4 chunk-set into a bf16 row buffer (thread t owns chunks t+i*1024)
__device__ __forceinline__ void stage_row(uint16_t* buf, int t, const f32x4 r[5]) {
    #pragma unroll
    for (int i = 0; i < 5; ++i) {
        int c = t + i * 1024;
        uint32_t lo, hi;
        asm("v_cvt_pk_bf16_f32 %0, %1, %2" : "=v"(lo) : "v"(r[i][0]), "v"(r[i][1]));
        asm("v_cvt_pk_bf16_f32 %0, %1, %2" : "=v"(hi) : "v"(r[i][2]), "v"(r[i][3]));
        uint2 p2; p2.x = lo; p2.y = hi;
        *(uint2*)&buf[c * 4] = p2;               // 8 B at byte offset c*8
    }
}

__device__ __forceinline__ void load_row(const float* __restrict__ xrow, int t, f32x4 r[5]) {
    #pragma unroll
    for (int i = 0; i < 5; ++i) {
        int c = t + i * 1024;
        int cs = c < 5000 ? c : 4999;            // tail clamp (chunks 5000..5119)
        r[i] = *(const f32x4*)(xrow + (size_t)cs * 4);
    }
}

// gather one row b from a bf16 buffer using packed idx (zero vmem loads)
__device__ __forceinline__ void gather_row(const uint16_t* buf, const uint32_t pk[16],
                                           int t, int b, uint32_t* __restrict__ G32) {
    #pragma unroll
    for (int it = 0; it < 8; ++it) {
        uint32_t pa = pk[2 * it], pb = pk[2 * it + 1];
        uint32_t f0 = buf[pa & 0xffffu], f1 = buf[pa >> 16];
        uint32_t f2 = buf[pb & 0xffffu], f3 = buf[pb >> 16];
        uint2 p;
        p.x = f0 | (f1 << 16);
        p.y = f2 | (f3 << 16);
        int j = t + it * 1024;
        int g = j >> 7, kq = j & 127;
        *(uint2*)&G32[(size_t)g * 262144 + (size_t)b * 256 + kq * 2] = p;
    }
}

// ---------------- K1: fat prep (832 blocks x 1024, 81920B dyn LDS) ----------------
// blocks [0,256):   wprep -- Wc[g][n][k] = (W1[g]@W2[g])^T bf16, g=bid>>2, mt=bid&3
// blocks [256,320): bias  -- bias2[g][n] = b1[g]@W2[g,:,n] + b2[g][n]
// blocks [320,832): gather -- rows 2*(bid-320), +1, bf16 dbuf pipeline
__global__ __launch_bounds__(1024, 8) void k_prep(const float* __restrict__ x,
                                                  const int* __restrict__ idx,
                                                  const float* __restrict__ W1,
                                                  const float* __restrict__ b1,
                                                  const float* __restrict__ W2,
                                                  const float* __restrict__ b2,
                                                  uint16_t* __restrict__ Wc,
                                                  float* __restrict__ bias2,
                                                  uint32_t* __restrict__ G32) {
    extern __shared__ __align__(16) uint8_t smem[];   // 81920 B
    const int bid = blockIdx.x;
    const int t = threadIdx.x;

    if (bid < 256) {
        // ---- wprep: 16 waves as 4x4; wave tile 32(m=k of Wc^T) x 32(n); BK=32 ----
        uint16_t* As = (uint16_t*)smem;             // [128][40]
        uint16_t* Bs = As + 5120;                   // [32][132]
        const int g = bid >> 2, mt = bid & 3;
        const int wid = t >> 6, l = t & 63;
        const int wm = wid >> 2, wn = wid & 3;
        const int q = l >> 4, lm = l & 15;
        const float* W1g = W1 + ((size_t)g * 512 + (size_t)mt * 128) * 256;
        const float* W2g = W2 + (size_t)g * 256 * 128;
        f32x4 acc[2][2];
        #pragma unroll
        for (int mi = 0; mi < 2; ++mi)
            #pragma unroll
            for (int ni = 0; ni < 2; ++ni) {
                f32x4 z = {0.f, 0.f, 0.f, 0.f};
                acc[mi][ni] = z;
            }
        for (int kt = 0; kt < 8; ++kt) {
            __syncthreads();
            {   // A: 128 x 32 f32 -> bf16 (1024 f32x4, 1/thread)
                int m = t >> 3, c4 = t & 7;
                f32x4 v = *(const f32x4*)(W1g + (size_t)m * 256 + kt * 32 + c4 * 4);
                *(uint64_t*)&As[m * 40 + c4 * 4] = pack4bf(v);
            }
            {   // B: 32(h) x 128(n)
                int h = t >> 5, n4 = t & 31;
                f32x4 v = *(const f32x4*)(W2g + (size_t)(kt * 32 + h) * 128 + n4 * 4);
                *(uint64_t*)&Bs[h * 132 + n4 * 4] = pack4bf(v);
            }
            __syncthreads();
            bf16x8 a[2];
            #pragma unroll
            for (int mi = 0; mi < 2; ++mi)
                a[mi] = *(const bf16x8*)&As[(wm * 32 + mi * 16 + lm) * 40 + q * 8];
            #pragma unroll
            for (int ni = 0; ni < 2; ++ni) {
                int n = wn * 32 + ni * 16 + lm;
                u16x8 bu;
                #pragma unroll
                for (int j = 0; j < 8; ++j) bu[j] = Bs[(q * 8 + j) * 132 + n];
                bf16x8 bv = __builtin_bit_cast(bf16x8, bu);
                #pragma unroll
                for (int mi = 0; mi < 2; ++mi)
                    acc[mi][ni] = __builtin_amdgcn_mfma_f32_16x16x32_bf16(a[mi], bv, acc[mi][ni], 0, 0, 0);
            }
        }
        uint16_t* Wcg = Wc + (size_t)g * 128 * 512;
        #pragma unroll
        for (int mi = 0; mi < 2; ++mi) {
            int k0 = mt * 128 + wm * 32 + mi * 16 + q * 4;
            #pragma unroll
            for (int ni = 0; ni < 2; ++ni) {
                int n = wn * 32 + ni * 16 + lm;
                *(uint64_t*)&Wcg[(size_t)n * 512 + k0] = pack4bf(acc[mi][ni]);
            }
        }
    } else if (bid < 320) {
        // ---- bias2[g][n] = b1[g] @ W2[g,:,n] + b2[g][n] ----
        if (t < 128) {
            const int g = bid - 256, n = t;
            const float* w = W2 + (size_t)g * 256 * 128 + n;
            const float* bb = b1 + g * 256;
            float s = b2[g * 128 + n];
            for (int h = 0; h < 256; ++h) s += bb[h] * w[(size_t)h * 128];
            bias2[g * 128 + n] = s;
        }
    } else {
        // ---- gather: rows b0, b0+1; bf16 dbuf; per-row pipeline ----
        uint16_t* buf0 = (uint16_t*)smem;            // [20480] bf16 = 40960 B
        uint16_t* buf1 = buf0 + 20480;               // second 40960 B
        const int gb = bid - 320;
        const int b0 = gb * 2;
        const float* xr0 = x + (size_t)b0 * 20000;
        const float* xr1 = xr0 + 20000;

        // hoist idx, packed 2x16b per VGPR (indices < 20000 < 2^15)
        const int4* idx4 = (const int4*)idx;
        uint32_t pk[16];
        #pragma unroll
        for (int p = 0; p < 8; ++p) {
            int4 iv = idx4[t + p * 1024];
            pk[2 * p]     = (uint32_t)iv.x | ((uint32_t)iv.y << 16);
            pk[2 * p + 1] = (uint32_t)iv.z | ((uint32_t)iv.w << 16);
        }

        f32x4 r[5];
        load_row(xr0, t, r);                         // row0 -> regs
        stage_row(buf0, t, r);                       // cvt+write buf0
        __syncthreads();                             // buf0 ready

        load_row(xr1, t, r);                         // issue row1 loads (5 vmem)
        __builtin_amdgcn_sched_barrier(0);           // pin issue before gather
        gather_row(buf0, pk, t, b0, G32);            // zero vmem loads: row1 stays in flight
        __builtin_amdgcn_sched_barrier(0);           // don't hoist row1 wait above gather
        stage_row(buf1, t, r);                       // counted vmcnt wait; buf1 disjoint -> no barrier
        __syncthreads();                             // buf1 ready
        gather_row(buf1, pk, t, b0 + 1, G32);
    }
}

// ---------------- K2: out[b, g*128+n] = G[g] @ Wc[g]^T + bias2[g] ----------------
// m97-style: 128x128 tile, BK=64, global_load_lds(16), linear LDS, XOR swizzle
// via pre-swizzled global source (rule #21). Bijective XCD swizzle (512%8==0).
__global__ __launch_bounds__(256) void k_gemm(const uint16_t* __restrict__ G,
                                              const uint16_t* __restrict__ Wc,
                                              const float* __restrict__ bias2,
                                              float* __restrict__ out) {
    __shared__ uint16_t sh[16384];             // A: [0,8192), B: [8192,16384) elems
    uint16_t* As = sh;
    uint16_t* Bs = sh + 8192;
    const int wg = (blockIdx.x & 7) * 64 + (blockIdx.x >> 3);   // XCD swizzle
    const int g = wg >> 3, mt = wg & 7;
    const int t = threadIdx.x;
    const int wid = t >> 6, l = t & 63;
    const int wm = wid >> 1, wn = wid & 1;
    const int q = l >> 4, lm = l & 15;
    const int lrow = l >> 3;                     // 8 rows per 1KB chunk
    const int lcolsw = ((l & 7) ^ lrow) * 8;     // inverse-swizzled global col (elems)
    const uint16_t* Ga = G + (size_t)g * 524288 + (size_t)mt * 128 * 512;
    const uint16_t* Wa = Wc + (size_t)g * 65536;

    f32x4 acc[4][4];
    #pragma unroll
    for (int mi = 0; mi < 4; ++mi)
        #pragma unroll
        for (int ni = 0; ni < 4; ++ni) {
            f32x4 z = {0.f, 0.f, 0.f, 0.f};
            acc[mi][ni] = z;
        }

    for (int kt = 0; kt < 8; ++kt) {
        __syncthreads();                          // prev compute done before overwrite
        #pragma unroll
        for (int r = 0; r < 4; ++r) {
            const int rowbase = wid * 8 + r * 32; // wave-uniform, multiple of 8
            const uint16_t* sA = Ga + (size_t)(rowbase + lrow) * 512 + kt * 64 + lcolsw;
            const uint16_t* sB = Wa + (size_t)(rowbase + lrow) * 512 + kt * 64 + lcolsw;
            __builtin_amdgcn_global_load_lds(
                (const __attribute__((address_space(1))) void*)sA,
                (__attribute__((address_space(3))) void*)(As + rowbase * 64), 16, 0, 0);
            __builtin_amdgcn_global_load_lds(
                (const __attribute__((address_space(1))) void*)sB,
                (__attribute__((address_space(3))) void*)(Bs + rowbase * 64), 16, 0, 0);
        }
        __syncthreads();                          // drains vmcnt -> data visible
        #pragma unroll
        for (int kk = 0; kk < 2; ++kk) {
            bf16x8 a[4], b[4];
            #pragma unroll
            for (int mi = 0; mi < 4; ++mi) {
                int row = wm * 64 + mi * 16 + lm;
                int off = row * 64 + ((kk * 32 + q * 8) ^ ((lm & 7) * 8));
                a[mi] = *(const bf16x8*)&As[off];
            }
            #pragma unroll
            for (int ni = 0; ni < 4; ++ni) {
                int row = wn * 64 + ni * 16 + lm;
                int off = row * 64 + ((kk * 32 + q * 8) ^ ((lm & 7) * 8));
                b[ni] = *(const bf16x8*)&Bs[off];
            }
            #pragma unroll
            for (int mi = 0; mi < 4; ++mi)
                #pragma unroll
                for (int ni = 0; ni < 4; ++ni)
                    acc[mi][ni] = __builtin_amdgcn_mfma_f32_16x16x32_bf16(a[mi], b[ni], acc[mi][ni], 0, 0, 0);
        }
    }
    // epilogue: C/D layout col=lane&15, row=(lane>>4)*4+reg
    float bn[4];
    #pragma unroll
    for (int ni = 0; ni < 4; ++ni) bn[ni] = bias2[g * 128 + wn * 64 + ni * 16 + lm];
    #pragma unroll
    for (int mi = 0; mi < 4; ++mi)
        #pragma unroll
        for (int ni = 0; ni < 4; ++ni) {
            int col = g * 128 + wn * 64 + ni * 16 + lm;
            #pragma unroll
            for (int r = 0; r < 4; ++r) {
                int brow = mt * 128 + wm * 64 + mi * 16 + q * 4 + r;
                out[(size_t)brow * 8192 + col] = acc[mi][ni][r] + bn[ni];
            }
        }
}

extern "C" void kernel_launch(void* const* d_in, const int* in_sizes, int n_in,
                              void* d_out, int out_size, void* d_ws, size_t ws_size,
                              hipStream_t stream) {
    (void)in_sizes; (void)n_in; (void)out_size; (void)ws_size;
    const float* x   = (const float*)d_in[0];
    const int*   idx = (const int*)d_in[1];
    const float* W1  = (const float*)d_in[2];
    const float* b1  = (const float*)d_in[3];
    const float* W2  = (const float*)d_in[4];
    const float* b2  = (const float*)d_in[5];
    float* out = (float*)d_out;

    uint16_t* G     = (uint16_t*)d_ws;                                  // 64 MiB
    uint16_t* Wc    = (uint16_t*)((char*)d_ws + (size_t)(64 << 20));    //  8 MiB
    float*    bias2 = (float*)   ((char*)d_ws + (size_t)(72 << 20));    // 32 KiB

    k_prep<<<832, 1024, 81920, stream>>>(x, idx, W1, b1, W2, b2, Wc, bias2, (uint32_t*)G);
    k_gemm<<<512,  256, 0, stream>>>(G, Wc, bias2, out);
}

// Round 11
// 58.133 us; speedup vs baseline: 1.3137x; 1.3137x over previous
//
#include <hip/hip_runtime.h>
#include <hip/hip_bf16.h>
#include <stdint.h>

// Problem: B=1024, IN=20000, NG=64, GIN=512, H1=256, GS=128
// o = x[:,idx] @ (W1@W2) + (b1@W2 + b2)   -- linear-linear collapse
//
// ws layout: G bf16 [1024][32768] B-MAJOR @0 (64MiB), Wc bf16 [64][128][512]
// @64MiB (8MiB), bias2 f32 [64][128] @72MiB (32KB). ws >= 72MiB+32KB.
//
// R11 = R8 structure + G layout b-major (gather writes two CONTIGUOUS 64KB
// rows per block instead of 512B granules scattered over 64 slabs) + uint4
// stores. Theory: R8's 2.4TB/s gather was HBM row-thrash on writes.

typedef __attribute__((ext_vector_type(4))) float f32x4;
typedef __attribute__((ext_vector_type(8))) __bf16 bf16x8;
typedef __attribute__((ext_vector_type(8))) uint16_t u16x8;

__device__ __forceinline__ uint16_t f2bf(float f) {
    uint32_t u = __float_as_uint(f);
    u += 0x7FFFu + ((u >> 16) & 1u);   // RNE
    return (uint16_t)(u >> 16);
}

__device__ __forceinline__ uint64_t pack4bf(f32x4 v) {
    return (uint64_t)f2bf(v[0]) | ((uint64_t)f2bf(v[1]) << 16)
         | ((uint64_t)f2bf(v[2]) << 32) | ((uint64_t)f2bf(v[3]) << 48);
}

__device__ __forceinline__ uint32_t bf16lo(float f) {   // u32 = bf16(f) in low16
    uint32_t q;
    asm("v_cvt_pk_bf16_f32 %0, %1, 0" : "=v"(q) : "v"(f));
    return q;
}

// ---------------- K1: fat prep (832 blocks x 1024) ----------------
// blocks [0,256):   wprep -- Wc[g][n][k] = (W1[g]@W2[g])^T bf16, g=bid>>2, mt=bid&3
// blocks [256,320): bias  -- bias2[g][n] = b1[g]@W2[g,:,n] + b2[g][n]
// blocks [320,832): gather -- rows 2*(bid-320), +1, interleaved u32 staging,
//                   b-major contiguous uint4 stores
__global__ __launch_bounds__(1024, 8) void k_prep(const float* __restrict__ x,
                                                  const int* __restrict__ idx,
                                                  const float* __restrict__ W1,
                                                  const float* __restrict__ b1,
                                                  const float* __restrict__ W2,
                                                  const float* __restrict__ b2,
                                                  uint16_t* __restrict__ Wc,
                                                  float* __restrict__ bias2,
                                                  uint32_t* __restrict__ G32) {
    __shared__ __align__(16) uint8_t smem[81920];
    const int bid = blockIdx.x;
    const int t = threadIdx.x;

    if (bid < 256) {
        // ---- wprep: 16 waves as 4x4; wave tile 32(m=k of Wc^T) x 32(n); BK=32 ----
        uint16_t* As = (uint16_t*)smem;             // [128][40]
        uint16_t* Bs = As + 5120;                   // [32][132]
        const int g = bid >> 2, mt = bid & 3;
        const int wid = t >> 6, l = t & 63;
        const int wm = wid >> 2, wn = wid & 3;
        const int q = l >> 4, lm = l & 15;
        const float* W1g = W1 + ((size_t)g * 512 + (size_t)mt * 128) * 256;
        const float* W2g = W2 + (size_t)g * 256 * 128;
        f32x4 acc[2][2];
        #pragma unroll
        for (int mi = 0; mi < 2; ++mi)
            #pragma unroll
            for (int ni = 0; ni < 2; ++ni) {
                f32x4 z = {0.f, 0.f, 0.f, 0.f};
                acc[mi][ni] = z;
            }
        for (int kt = 0; kt < 8; ++kt) {
            __syncthreads();
            {   // A: 128 x 32 f32 -> bf16 (1024 f32x4, 1/thread)
                int m = t >> 3, c4 = t & 7;
                f32x4 v = *(const f32x4*)(W1g + (size_t)m * 256 + kt * 32 + c4 * 4);
                *(uint64_t*)&As[m * 40 + c4 * 4] = pack4bf(v);
            }
            {   // B: 32(h) x 128(n)
                int h = t >> 5, n4 = t & 31;
                f32x4 v = *(const f32x4*)(W2g + (size_t)(kt * 32 + h) * 128 + n4 * 4);
                *(uint64_t*)&Bs[h * 132 + n4 * 4] = pack4bf(v);
            }
            __syncthreads();
            bf16x8 a[2];
            #pragma unroll
            for (int mi = 0; mi < 2; ++mi)
                a[mi] = *(const bf16x8*)&As[(wm * 32 + mi * 16 + lm) * 40 + q * 8];
            #pragma unroll
            for (int ni = 0; ni < 2; ++ni) {
                int n = wn * 32 + ni * 16 + lm;
                u16x8 bu;
                #pragma unroll
                for (int j = 0; j < 8; ++j) bu[j] = Bs[(q * 8 + j) * 132 + n];
                bf16x8 bv = __builtin_bit_cast(bf16x8, bu);
                #pragma unroll
                for (int mi = 0; mi < 2; ++mi)
                    acc[mi][ni] = __builtin_amdgcn_mfma_f32_16x16x32_bf16(a[mi], bv, acc[mi][ni], 0, 0, 0);
            }
        }
        uint16_t* Wcg = Wc + (size_t)g * 128 * 512;
        #pragma unroll
        for (int mi = 0; mi < 2; ++mi) {
            int k0 = mt * 128 + wm * 32 + mi * 16 + q * 4;
            #pragma unroll
            for (int ni = 0; ni < 2; ++ni) {
                int n = wn * 32 + ni * 16 + lm;
                *(uint64_t*)&Wcg[(size_t)n * 512 + k0] = pack4bf(acc[mi][ni]);
            }
        }
    } else if (bid < 320) {
        // ---- bias2[g][n] = b1[g] @ W2[g,:,n] + b2[g][n] ----
        if (t < 128) {
            const int g = bid - 256, n = t;
            const float* w = W2 + (size_t)g * 256 * 128 + n;
            const float* bb = b1 + g * 256;
            float s = b2[g * 128 + n];
            for (int h = 0; h < 256; ++h) s += bb[h] * w[(size_t)h * 128];
            bias2[g * 128 + n] = s;
        }
    } else {
        // ---- gather: rows b0, b0+1 interleaved in u32 LDS; b-major stores ----
        uint32_t* sh32 = (uint32_t*)smem;            // [20480] u32
        const int gb = bid - 320;
        const int b0 = gb * 2, b1r = b0 + 1;
        const float* xr0 = x + (size_t)b0 * 20000;
        const float* xr1 = xr0 + 20000;

        f32x4 r0[5], r1[5];
        #pragma unroll
        for (int i = 0; i < 5; ++i) {
            int c = t + i * 1024;
            int cs = c < 5000 ? c : 4999;
            r0[i] = *(const f32x4*)(xr0 + (size_t)cs * 4);
        }
        #pragma unroll
        for (int i = 0; i < 5; ++i) {
            int c = t + i * 1024;
            int cs = c < 5000 ? c : 4999;
            r1[i] = *(const f32x4*)(xr1 + (size_t)cs * 4);
        }
        #pragma unroll
        for (int i = 0; i < 5; ++i) {                // row b0 -> low16 halves
            int c = t + i * 1024;
            uint4 qv;
            qv.x = bf16lo(r0[i][0]);
            qv.y = bf16lo(r0[i][1]);
            qv.z = bf16lo(r0[i][2]);
            qv.w = bf16lo(r0[i][3]);
            *(uint4*)&sh32[c * 4] = qv;
        }
        #pragma unroll
        for (int i = 0; i < 5; ++i) {                // row b0+1 -> high16 halves
            int c = t + i * 1024;
            uint16_t* hp = (uint16_t*)&sh32[c * 4];
            #pragma unroll
            for (int j = 0; j < 4; ++j)
                hp[j * 2 + 1] = (uint16_t)bf16lo(r1[i][j]);
        }
        __syncthreads();                             // both rows staged

        // gather: 4 iters x 8 features/thread; b-major rows -> 16B contig stores
        const int4* idx4 = (const int4*)idx;
        uint32_t* rowA = G32 + (size_t)b0 * 16384;   // 64KB row (u32 pitch 16384)
        uint32_t* rowB = G32 + (size_t)b1r * 16384;
        #pragma unroll
        for (int it = 0; it < 4; ++it) {
            int j8 = t + it * 1024;                  // 8-feature chunk, [0,4096)
            int4 va = idx4[j8 * 2];
            int4 vb = idx4[j8 * 2 + 1];
            uint32_t f0 = sh32[va.x], f1 = sh32[va.y];
            uint32_t f2 = sh32[va.z], f3 = sh32[va.w];
            uint32_t f4 = sh32[vb.x], f5 = sh32[vb.y];
            uint32_t f6 = sh32[vb.z], f7 = sh32[vb.w];
            uint4 p0, p1;
            p0.x = __builtin_amdgcn_perm(f1, f0, 0x05040100u);  // b0: lo16s
            p0.y = __builtin_amdgcn_perm(f3, f2, 0x05040100u);
            p0.z = __builtin_amdgcn_perm(f5, f4, 0x05040100u);
            p0.w = __builtin_amdgcn_perm(f7, f6, 0x05040100u);
            p1.x = __builtin_amdgcn_perm(f1, f0, 0x07060302u);  // b1: hi16s
            p1.y = __builtin_amdgcn_perm(f3, f2, 0x07060302u);
            p1.z = __builtin_amdgcn_perm(f5, f4, 0x07060302u);
            p1.w = __builtin_amdgcn_perm(f7, f6, 0x07060302u);
            *(uint4*)&rowA[j8 * 4] = p0;             // 16B at row offset j8*16B
            *(uint4*)&rowB[j8 * 4] = p1;
        }
    }
}

// ---------------- K2: out[b, g*128+n] = G[b] @ Wc[g]^T + bias2[g] ----------------
// m97-style: 128x128 tile, BK=64, global_load_lds(16), linear LDS, XOR swizzle
// via pre-swizzled global source (rule #21). Bijective XCD swizzle (512%8==0).
// G is b-major: row pitch 32768 elems; block (g,mt) reads rows mt*128..+128,
// cols g*512..+512.
__global__ __launch_bounds__(256) void k_gemm(const uint16_t* __restrict__ G,
                                              const uint16_t* __restrict__ Wc,
                                              const float* __restrict__ bias2,
                                              float* __restrict__ out) {
    __shared__ uint16_t sh[16384];             // A: [0,8192), B: [8192,16384) elems
    uint16_t* As = sh;
    uint16_t* Bs = sh + 8192;
    const int wg = (blockIdx.x & 7) * 64 + (blockIdx.x >> 3);   // XCD swizzle
    const int g = wg >> 3, mt = wg & 7;
    const int t = threadIdx.x;
    const int wid = t >> 6, l = t & 63;
    const int wm = wid >> 1, wn = wid & 1;
    const int q = l >> 4, lm = l & 15;
    const int lrow = l >> 3;                     // 8 rows per 1KB chunk
    const int lcolsw = ((l & 7) ^ lrow) * 8;     // inverse-swizzled global col (elems)
    const uint16_t* Ga = G + (size_t)mt * 128 * 32768 + (size_t)g * 512;  // b-major
    const uint16_t* Wa = Wc + (size_t)g * 65536;

    f32x4 acc[4][4];
    #pragma unroll
    for (int mi = 0; mi < 4; ++mi)
        #pragma unroll
        for (int ni = 0; ni < 4; ++ni) {
            f32x4 z = {0.f, 0.f, 0.f, 0.f};
            acc[mi][ni] = z;
        }

    for (int kt = 0; kt < 8; ++kt) {
        __syncthreads();                          // prev compute done before overwrite
        #pragma unroll
        for (int r = 0; r < 4; ++r) {
            const int rowbase = wid * 8 + r * 32; // wave-uniform, multiple of 8
            const uint16_t* sA = Ga + (size_t)(rowbase + lrow) * 32768 + kt * 64 + lcolsw;
            const uint16_t* sB = Wa + (size_t)(rowbase + lrow) * 512 + kt * 64 + lcolsw;
            __builtin_amdgcn_global_load_lds(
                (const __attribute__((address_space(1))) void*)sA,
                (__attribute__((address_space(3))) void*)(As + rowbase * 64), 16, 0, 0);
            __builtin_amdgcn_global_load_lds(
                (const __attribute__((address_space(1))) void*)sB,
                (__attribute__((address_space(3))) void*)(Bs + rowbase * 64), 16, 0, 0);
        }
        __syncthreads();                          // drains vmcnt -> data visible
        #pragma unroll
        for (int kk = 0; kk < 2; ++kk) {
            bf16x8 a[4], b[4];
            #pragma unroll
            for (int mi = 0; mi < 4; ++mi) {
                int row = wm * 64 + mi * 16 + lm;
                int off = row * 64 + ((kk * 32 + q * 8) ^ ((lm & 7) * 8));
                a[mi] = *(const bf16x8*)&As[off];
            }
            #pragma unroll
            for (int ni = 0; ni < 4; ++ni) {
                int row = wn * 64 + ni * 16 + lm;
                int off = row * 64 + ((kk * 32 + q * 8) ^ ((lm & 7) * 8));
                b[ni] = *(const bf16x8*)&Bs[off];
            }
            #pragma unroll
            for (int mi = 0; mi < 4; ++mi)
                #pragma unroll
                for (int ni = 0; ni < 4; ++ni)
                    acc[mi][ni] = __builtin_amdgcn_mfma_f32_16x16x32_bf16(a[mi], b[ni], acc[mi][ni], 0, 0, 0);
        }
    }
    // epilogue: C/D layout col=lane&15, row=(lane>>4)*4+reg
    float bn[4];
    #pragma unroll
    for (int ni = 0; ni < 4; ++ni) bn[ni] = bias2[g * 128 + wn * 64 + ni * 16 + lm];
    #pragma unroll
    for (int mi = 0; mi < 4; ++mi)
        #pragma unroll
        for (int ni = 0; ni < 4; ++ni) {
            int col = g * 128 + wn * 64 + ni * 16 + lm;
            #pragma unroll
            for (int r = 0; r < 4; ++r) {
                int brow = mt * 128 + wm * 64 + mi * 16 + q * 4 + r;
                out[(size_t)brow * 8192 + col] = acc[mi][ni][r] + bn[ni];
            }
        }
}

extern "C" void kernel_launch(void* const* d_in, const int* in_sizes, int n_in,
                              void* d_out, int out_size, void* d_ws, size_t ws_size,
                              hipStream_t stream) {
    (void)in_sizes; (void)n_in; (void)out_size; (void)ws_size;
    const float* x   = (const float*)d_in[0];
    const int*   idx = (const int*)d_in[1];
    const float* W1  = (const float*)d_in[2];
    const float* b1  = (const float*)d_in[3];
    const float* W2  = (const float*)d_in[4];
    const float* b2  = (const float*)d_in[5];
    float* out = (float*)d_out;

    uint16_t* G     = (uint16_t*)d_ws;                                  // 64 MiB
    uint16_t* Wc    = (uint16_t*)((char*)d_ws + (size_t)(64 << 20));    //  8 MiB
    float*    bias2 = (float*)   ((char*)d_ws + (size_t)(72 << 20));    // 32 KiB

    k_prep<<<832, 1024, 0, stream>>>(x, idx, W1, b1, W2, b2, Wc, bias2, (uint32_t*)G);
    k_gemm<<<512,  256, 0, stream>>>(G, Wc, bias2, out);
}

// Round 12
// 57.448 us; speedup vs baseline: 1.3293x; 1.0119x over previous
//
#include <hip/hip_runtime.h>
#include <hip/hip_bf16.h>
#include <stdint.h>

// Problem: B=1024, IN=20000, NG=64, GIN=512, H1=256, GS=128
// o = x[:,idx] @ (W1@W2) + (b1@W2 + b2)   -- linear-linear collapse
//
// ws layout: G bf16 [1024][32768] B-MAJOR @0 (64MiB), Wc bf16 [64][128][512]
// @64MiB (8MiB), bias2 f32 [64][128] @72MiB (32KB). ws >= 72MiB+32KB.
//
// R12 = R11 with k_prep UNCHANGED (control); k_gemm retiled 64x128 ->
// 1024 blocks, 24KB LDS, 4 blocks/CU = 16 waves/CU (was 8). One-variable
// probe: if gemm was latency-bound, total drops ~5us; if unchanged, gemm
// was already near-floor and prep owns the remaining gap.

typedef __attribute__((ext_vector_type(4))) float f32x4;
typedef __attribute__((ext_vector_type(8))) __bf16 bf16x8;
typedef __attribute__((ext_vector_type(8))) uint16_t u16x8;

__device__ __forceinline__ uint16_t f2bf(float f) {
    uint32_t u = __float_as_uint(f);
    u += 0x7FFFu + ((u >> 16) & 1u);   // RNE
    return (uint16_t)(u >> 16);
}

__device__ __forceinline__ uint64_t pack4bf(f32x4 v) {
    return (uint64_t)f2bf(v[0]) | ((uint64_t)f2bf(v[1]) << 16)
         | ((uint64_t)f2bf(v[2]) << 32) | ((uint64_t)f2bf(v[3]) << 48);
}

__device__ __forceinline__ uint32_t bf16lo(float f) {   // u32 = bf16(f) in low16
    uint32_t q;
    asm("v_cvt_pk_bf16_f32 %0, %1, 0" : "=v"(q) : "v"(f));
    return q;
}

// ---------------- K1: fat prep (832 blocks x 1024) -- UNCHANGED from R11 ----
__global__ __launch_bounds__(1024, 8) void k_prep(const float* __restrict__ x,
                                                  const int* __restrict__ idx,
                                                  const float* __restrict__ W1,
                                                  const float* __restrict__ b1,
                                                  const float* __restrict__ W2,
                                                  const float* __restrict__ b2,
                                                  uint16_t* __restrict__ Wc,
                                                  float* __restrict__ bias2,
                                                  uint32_t* __restrict__ G32) {
    __shared__ __align__(16) uint8_t smem[81920];
    const int bid = blockIdx.x;
    const int t = threadIdx.x;

    if (bid < 256) {
        // ---- wprep: 16 waves as 4x4; wave tile 32(m=k of Wc^T) x 32(n); BK=32 ----
        uint16_t* As = (uint16_t*)smem;             // [128][40]
        uint16_t* Bs = As + 5120;                   // [32][132]
        const int g = bid >> 2, mt = bid & 3;
        const int wid = t >> 6, l = t & 63;
        const int wm = wid >> 2, wn = wid & 3;
        const int q = l >> 4, lm = l & 15;
        const float* W1g = W1 + ((size_t)g * 512 + (size_t)mt * 128) * 256;
        const float* W2g = W2 + (size_t)g * 256 * 128;
        f32x4 acc[2][2];
        #pragma unroll
        for (int mi = 0; mi < 2; ++mi)
            #pragma unroll
            for (int ni = 0; ni < 2; ++ni) {
                f32x4 z = {0.f, 0.f, 0.f, 0.f};
                acc[mi][ni] = z;
            }
        for (int kt = 0; kt < 8; ++kt) {
            __syncthreads();
            {   // A: 128 x 32 f32 -> bf16 (1024 f32x4, 1/thread)
                int m = t >> 3, c4 = t & 7;
                f32x4 v = *(const f32x4*)(W1g + (size_t)m * 256 + kt * 32 + c4 * 4);
                *(uint64_t*)&As[m * 40 + c4 * 4] = pack4bf(v);
            }
            {   // B: 32(h) x 128(n)
                int h = t >> 5, n4 = t & 31;
                f32x4 v = *(const f32x4*)(W2g + (size_t)(kt * 32 + h) * 128 + n4 * 4);
                *(uint64_t*)&Bs[h * 132 + n4 * 4] = pack4bf(v);
            }
            __syncthreads();
            bf16x8 a[2];
            #pragma unroll
            for (int mi = 0; mi < 2; ++mi)
                a[mi] = *(const bf16x8*)&As[(wm * 32 + mi * 16 + lm) * 40 + q * 8];
            #pragma unroll
            for (int ni = 0; ni < 2; ++ni) {
                int n = wn * 32 + ni * 16 + lm;
                u16x8 bu;
                #pragma unroll
                for (int j = 0; j < 8; ++j) bu[j] = Bs[(q * 8 + j) * 132 + n];
                bf16x8 bv = __builtin_bit_cast(bf16x8, bu);
                #pragma unroll
                for (int mi = 0; mi < 2; ++mi)
                    acc[mi][ni] = __builtin_amdgcn_mfma_f32_16x16x32_bf16(a[mi], bv, acc[mi][ni], 0, 0, 0);
            }
        }
        uint16_t* Wcg = Wc + (size_t)g * 128 * 512;
        #pragma unroll
        for (int mi = 0; mi < 2; ++mi) {
            int k0 = mt * 128 + wm * 32 + mi * 16 + q * 4;
            #pragma unroll
            for (int ni = 0; ni < 2; ++ni) {
                int n = wn * 32 + ni * 16 + lm;
                *(uint64_t*)&Wcg[(size_t)n * 512 + k0] = pack4bf(acc[mi][ni]);
            }
        }
    } else if (bid < 320) {
        // ---- bias2[g][n] = b1[g] @ W2[g,:,n] + b2[g][n] ----
        if (t < 128) {
            const int g = bid - 256, n = t;
            const float* w = W2 + (size_t)g * 256 * 128 + n;
            const float* bb = b1 + g * 256;
            float s = b2[g * 128 + n];
            for (int h = 0; h < 256; ++h) s += bb[h] * w[(size_t)h * 128];
            bias2[g * 128 + n] = s;
        }
    } else {
        // ---- gather: rows b0, b0+1 interleaved in u32 LDS; b-major stores ----
        uint32_t* sh32 = (uint32_t*)smem;            // [20480] u32
        const int gb = bid - 320;
        const int b0 = gb * 2, b1r = b0 + 1;
        const float* xr0 = x + (size_t)b0 * 20000;
        const float* xr1 = xr0 + 20000;

        f32x4 r0[5], r1[5];
        #pragma unroll
        for (int i = 0; i < 5; ++i) {
            int c = t + i * 1024;
            int cs = c < 5000 ? c : 4999;
            r0[i] = *(const f32x4*)(xr0 + (size_t)cs * 4);
        }
        #pragma unroll
        for (int i = 0; i < 5; ++i) {
            int c = t + i * 1024;
            int cs = c < 5000 ? c : 4999;
            r1[i] = *(const f32x4*)(xr1 + (size_t)cs * 4);
        }
        #pragma unroll
        for (int i = 0; i < 5; ++i) {                // row b0 -> low16 halves
            int c = t + i * 1024;
            uint4 qv;
            qv.x = bf16lo(r0[i][0]);
            qv.y = bf16lo(r0[i][1]);
            qv.z = bf16lo(r0[i][2]);
            qv.w = bf16lo(r0[i][3]);
            *(uint4*)&sh32[c * 4] = qv;
        }
        #pragma unroll
        for (int i = 0; i < 5; ++i) {                // row b0+1 -> high16 halves
            int c = t + i * 1024;
            uint16_t* hp = (uint16_t*)&sh32[c * 4];
            #pragma unroll
            for (int j = 0; j < 4; ++j)
                hp[j * 2 + 1] = (uint16_t)bf16lo(r1[i][j]);
        }
        __syncthreads();                             // both rows staged

        // gather: 4 iters x 8 features/thread; b-major rows -> 16B contig stores
        const int4* idx4 = (const int4*)idx;
        uint32_t* rowA = G32 + (size_t)b0 * 16384;   // 64KB row (u32 pitch 16384)
        uint32_t* rowB = G32 + (size_t)b1r * 16384;
        #pragma unroll
        for (int it = 0; it < 4; ++it) {
            int j8 = t + it * 1024;                  // 8-feature chunk, [0,4096)
            int4 va = idx4[j8 * 2];
            int4 vb = idx4[j8 * 2 + 1];
            uint32_t f0 = sh32[va.x], f1 = sh32[va.y];
            uint32_t f2 = sh32[va.z], f3 = sh32[va.w];
            uint32_t f4 = sh32[vb.x], f5 = sh32[vb.y];
            uint32_t f6 = sh32[vb.z], f7 = sh32[vb.w];
            uint4 p0, p1;
            p0.x = __builtin_amdgcn_perm(f1, f0, 0x05040100u);  // b0: lo16s
            p0.y = __builtin_amdgcn_perm(f3, f2, 0x05040100u);
            p0.z = __builtin_amdgcn_perm(f5, f4, 0x05040100u);
            p0.w = __builtin_amdgcn_perm(f7, f6, 0x05040100u);
            p1.x = __builtin_amdgcn_perm(f1, f0, 0x07060302u);  // b1: hi16s
            p1.y = __builtin_amdgcn_perm(f3, f2, 0x07060302u);
            p1.z = __builtin_amdgcn_perm(f5, f4, 0x07060302u);
            p1.w = __builtin_amdgcn_perm(f7, f6, 0x07060302u);
            *(uint4*)&rowA[j8 * 4] = p0;             // 16B at row offset j8*16B
            *(uint4*)&rowB[j8 * 4] = p1;
        }
    }
}

// ---------------- K2: out[b, g*128+n] = G[b] @ Wc[g]^T + bias2[g] ----------------
// R12: 64x128 tile (M=64 b-rows, N=128 = full group), 1024 blocks, 256 thr,
// 4 waves as 2x2 (wave tile 32x64), LDS 24KB -> 4 blocks/CU = 16 waves/CU.
// Same global_load_lds + XOR-swizzle scheme as R11 (verified formulas).
__global__ __launch_bounds__(256) void k_gemm(const uint16_t* __restrict__ G,
                                              const uint16_t* __restrict__ Wc,
                                              const float* __restrict__ bias2,
                                              float* __restrict__ out) {
    __shared__ uint16_t sh[12288];               // A: [0,4096), B: [4096,12288)
    uint16_t* As = sh;                           // [64][64]
    uint16_t* Bs = sh + 4096;                    // [128][64]
    const int wg = (blockIdx.x & 7) * 128 + (blockIdx.x >> 3);   // XCD swizzle (1024%8==0)
    const int g = wg >> 4, mt = wg & 15;         // 64 g x 16 mtiles
    const int t = threadIdx.x;
    const int wid = t >> 6, l = t & 63;
    const int wm = wid >> 1, wn = wid & 1;       // 2x2 waves, 32(m) x 64(n) each
    const int q = l >> 4, lm = l & 15;
    const int lrow = l >> 3;                     // 8 rows per wave-issue
    const int lcolsw = ((l & 7) ^ lrow) * 8;     // inverse-swizzled global col (elems)
    const uint16_t* Ga = G + (size_t)mt * 64 * 32768 + (size_t)g * 512;  // b-major
    const uint16_t* Wa = Wc + (size_t)g * 65536;

    f32x4 acc[2][4];
    #pragma unroll
    for (int mi = 0; mi < 2; ++mi)
        #pragma unroll
        for (int ni = 0; ni < 4; ++ni) {
            f32x4 z = {0.f, 0.f, 0.f, 0.f};
            acc[mi][ni] = z;
        }

    for (int kt = 0; kt < 8; ++kt) {
        __syncthreads();                          // prev compute done before overwrite
        #pragma unroll
        for (int i = 0; i < 2; ++i) {             // A: 64 rows
            const int rowbase = wid * 8 + i * 32; // wave-uniform
            const uint16_t* sA = Ga + (size_t)(rowbase + lrow) * 32768 + kt * 64 + lcolsw;
            __builtin_amdgcn_global_load_lds(
                (const __attribute__((address_space(1))) void*)sA,
                (__attribute__((address_space(3))) void*)(As + rowbase * 64), 16, 0, 0);
        }
        #pragma unroll
        for (int i = 0; i < 4; ++i) {             // B: 128 rows
            const int rowbase = wid * 8 + i * 32;
            const uint16_t* sB = Wa + (size_t)(rowbase + lrow) * 512 + kt * 64 + lcolsw;
            __builtin_amdgcn_global_load_lds(
                (const __attribute__((address_space(1))) void*)sB,
                (__attribute__((address_space(3))) void*)(Bs + rowbase * 64), 16, 0, 0);
        }
        __syncthreads();                          // drains vmcnt -> data visible
        #pragma unroll
        for (int kk = 0; kk < 2; ++kk) {
            bf16x8 a[2], b[4];
            #pragma unroll
            for (int mi = 0; mi < 2; ++mi) {
                int row = wm * 32 + mi * 16 + lm;
                int off = row * 64 + ((kk * 32 + q * 8) ^ ((lm & 7) * 8));
                a[mi] = *(const bf16x8*)&As[off];
            }
            #pragma unroll
            for (int ni = 0; ni < 4; ++ni) {
                int row = wn * 64 + ni * 16 + lm;
                int off = row * 64 + ((kk * 32 + q * 8) ^ ((lm & 7) * 8));
                b[ni] = *(const bf16x8*)&Bs[off];
            }
            #pragma unroll
            for (int mi = 0; mi < 2; ++mi)
                #pragma unroll
                for (int ni = 0; ni < 4; ++ni)
                    acc[mi][ni] = __builtin_amdgcn_mfma_f32_16x16x32_bf16(a[mi], b[ni], acc[mi][ni], 0, 0, 0);
        }
    }
    // epilogue: C/D layout col=lane&15, row=(lane>>4)*4+reg
    float bn[4];
    #pragma unroll
    for (int ni = 0; ni < 4; ++ni) bn[ni] = bias2[g * 128 + wn * 64 + ni * 16 + lm];
    #pragma unroll
    for (int mi = 0; mi < 2; ++mi)
        #pragma unroll
        for (int ni = 0; ni < 4; ++ni) {
            int col = g * 128 + wn * 64 + ni * 16 + lm;
            #pragma unroll
            for (int r = 0; r < 4; ++r) {
                int brow = mt * 64 + wm * 32 + mi * 16 + q * 4 + r;
                out[(size_t)brow * 8192 + col] = acc[mi][ni][r] + bn[ni];
            }
        }
}

extern "C" void kernel_launch(void* const* d_in, const int* in_sizes, int n_in,
                              void* d_out, int out_size, void* d_ws, size_t ws_size,
                              hipStream_t stream) {
    (void)in_sizes; (void)n_in; (void)out_size; (void)ws_size;
    const float* x   = (const float*)d_in[0];
    const int*   idx = (const int*)d_in[1];
    const float* W1  = (const float*)d_in[2];
    const float* b1  = (const float*)d_in[3];
    const float* W2  = (const float*)d_in[4];
    const float* b2  = (const float*)d_in[5];
    float* out = (float*)d_out;

    uint16_t* G     = (uint16_t*)d_ws;                                  // 64 MiB
    uint16_t* Wc    = (uint16_t*)((char*)d_ws + (size_t)(64 << 20));    //  8 MiB
    float*    bias2 = (float*)   ((char*)d_ws + (size_t)(72 << 20));    // 32 KiB

    k_prep<<<832, 1024, 0, stream>>>(x, idx, W1, b1, W2, b2, Wc, bias2, (uint32_t*)G);
    k_gemm<<<1024, 256, 0, stream>>>(G, Wc, bias2, out);
}